// Round 1
// baseline (116.224 us; speedup 1.0000x reference)
//
#include <hip/hip_runtime.h>

#ifndef B_GRAPHS
#define B_GRAPHS 512
#endif

// Kernel 1: offsets[b] = lower_bound(batch_vector, b) for b in [0, B].
// batch_vector is sorted, so offsets[b] is both the cumsum-of-sizes offset
// and the first-occurrence index; sizes[b] = offsets[b+1] - offsets[b].
__global__ void compute_offsets_kernel(const int* __restrict__ bv, int n,
                                       int num_graphs, int* __restrict__ offs) {
    int b = blockIdx.x * blockDim.x + threadIdx.x;
    if (b > num_graphs) return;
    int lo = 0, hi = n;
    while (lo < hi) {
        int mid = (lo + hi) >> 1;
        if (bv[mid] < b) lo = mid + 1; else hi = mid;
    }
    offs[b] = lo;
}

// Kernel 2: gather-formulated unbatch+pad. One 32-lane group per output row
// (b, pos). Row's source node = offs[b] + pos if pos < size_b, else zero-fill.
// Each lane moves one float4 (D = 128 floats = 32 x float4).
__global__ void gather_pad_kernel(const float4* __restrict__ vals4,
                                  const int* __restrict__ y,
                                  const int* __restrict__ offs,
                                  float4* __restrict__ enc4,
                                  float* __restrict__ tgt,
                                  float* __restrict__ msk,
                                  int max_len, int total_rows) {
    int row  = blockIdx.x * (blockDim.x >> 5) + (threadIdx.x >> 5);
    int lane = threadIdx.x & 31;
    if (row >= total_rows) return;

    int b    = row / max_len;
    int pos  = row - b * max_len;
    int start = offs[b];
    int size  = offs[b + 1] - start;

    bool valid = (pos < size);
    int node = start + pos;

    float4 v = make_float4(0.f, 0.f, 0.f, 0.f);
    if (valid) v = vals4[(size_t)node * 32 + lane];
    enc4[(size_t)row * 32 + lane] = v;

    if (lane == 0) {
        tgt[row] = valid ? (float)y[node] : 0.0f;
        msk[row] = valid ? 1.0f : 0.0f;
    }
}

extern "C" void kernel_launch(void* const* d_in, const int* in_sizes, int n_in,
                              void* d_out, int out_size, void* d_ws, size_t ws_size,
                              hipStream_t stream) {
    const float* values = (const float*)d_in[0];
    const int*   y      = (const int*)d_in[1];
    const int*   bv     = (const int*)d_in[2];
    // d_in[3] = num_graphs (device scalar); B is a compile-time constant in
    // the reference (512) and we need it on the host for grid math.

    const int N = in_sizes[1];            // 500000 nodes
    const int D = in_sizes[0] / N;        // 128
    const int B = B_GRAPHS;               // 512
    const int max_len = out_size / (B * (D + 2));
    const int total_rows = B * max_len;

    int* offs = (int*)d_ws;               // B+1 ints

    // offsets
    {
        int threads = 256;
        int blocks = (B + 1 + threads - 1) / threads;
        compute_offsets_kernel<<<blocks, threads, 0, stream>>>(bv, N, B, offs);
    }

    // gather + pad: writes every element of d_out exactly once (no memset).
    {
        float4* enc4 = (float4*)d_out;
        float*  tgt  = (float*)d_out + (size_t)total_rows * D;
        float*  msk  = (float*)d_out + (size_t)total_rows * (D + 1);
        int threads = 256;                         // 8 rows per block
        int rows_per_block = threads >> 5;
        int blocks = (total_rows + rows_per_block - 1) / rows_per_block;
        gather_pad_kernel<<<blocks, threads, 0, stream>>>(
            (const float4*)values, y, offs, enc4, tgt, msk, max_len, total_rows);
    }
}

// Round 2
// 101.671 us; speedup vs baseline: 1.1431x; 1.1431x over previous
//
#include <hip/hip_runtime.h>

#ifndef B_GRAPHS
#define B_GRAPHS 512
#endif

#define ROWS_PER_GROUP 4

typedef float f32x4 __attribute__((ext_vector_type(4)));

// Kernel 1: offsets[b] = lower_bound(batch_vector, b) for b in [0, B].
// batch_vector sorted => offsets[b] is both cumsum-of-sizes and
// first-occurrence index; sizes[b] = offsets[b+1] - offsets[b].
__global__ void compute_offsets_kernel(const int* __restrict__ bv, int n,
                                       int num_graphs, int* __restrict__ offs) {
    int b = blockIdx.x * blockDim.x + threadIdx.x;
    if (b > num_graphs) return;
    int lo = 0, hi = n;
    while (lo < hi) {
        int mid = (lo + hi) >> 1;
        if (bv[mid] < b) lo = mid + 1; else hi = mid;
    }
    offs[b] = lo;
}

// Kernel 2: gather-formulated unbatch+pad.
// grid.y = graph index b (offs loads become wave-uniform scalar loads, no
// integer division). Each 32-lane group handles ROWS_PER_GROUP consecutive
// rows of graph b; each lane moves one float4 per row (D=128 = 32*float4).
// Nontemporal: values are read once, enc is written once — skip L2 pollution.
__global__ void gather_pad_kernel(const f32x4* __restrict__ vals4,
                                  const int* __restrict__ y,
                                  const int* __restrict__ offs,
                                  f32x4* __restrict__ enc4,
                                  float* __restrict__ tgt,
                                  float* __restrict__ msk,
                                  int max_len) {
    const int b     = blockIdx.y;
    const int start = offs[b];           // uniform -> s_load
    const int size  = offs[b + 1] - start;

    const int group = threadIdx.x >> 5;
    const int lane  = threadIdx.x & 31;
    const int groups_per_block = blockDim.x >> 5;
    const int pos0 = (blockIdx.x * groups_per_block + group) * ROWS_PER_GROUP;

    // Issue up to 4 independent 16B loads before any store (MLP).
    f32x4 v[ROWS_PER_GROUP];
    #pragma unroll
    for (int r = 0; r < ROWS_PER_GROUP; ++r) {
        int pos = pos0 + r;
        f32x4 z = {0.f, 0.f, 0.f, 0.f};
        v[r] = z;
        if (pos < size)
            v[r] = __builtin_nontemporal_load(&vals4[(size_t)(start + pos) * 32 + lane]);
    }

    const size_t rowbase = (size_t)b * max_len + pos0;
    #pragma unroll
    for (int r = 0; r < ROWS_PER_GROUP; ++r) {
        int pos = pos0 + r;
        if (pos < max_len)
            __builtin_nontemporal_store(v[r], &enc4[(rowbase + r) * 32 + lane]);
    }

    // targets + mask: lanes 0/1 split the two scalar streams.
    if (lane < 2) {
        #pragma unroll
        for (int r = 0; r < ROWS_PER_GROUP; ++r) {
            int pos = pos0 + r;
            if (pos < max_len) {
                bool valid = pos < size;
                if (lane == 0)
                    tgt[rowbase + r] = valid ? (float)y[start + pos] : 0.0f;
                else
                    msk[rowbase + r] = valid ? 1.0f : 0.0f;
            }
        }
    }
}

extern "C" void kernel_launch(void* const* d_in, const int* in_sizes, int n_in,
                              void* d_out, int out_size, void* d_ws, size_t ws_size,
                              hipStream_t stream) {
    const float* values = (const float*)d_in[0];
    const int*   y      = (const int*)d_in[1];
    const int*   bv     = (const int*)d_in[2];

    const int N = in_sizes[1];            // 500000 nodes
    const int D = in_sizes[0] / N;        // 128
    const int B = B_GRAPHS;               // 512 (compile-time in reference)
    const int max_len = out_size / (B * (D + 2));
    const int total_rows = B * max_len;

    int* offs = (int*)d_ws;               // B+1 ints

    {
        int threads = 256;
        int blocks = (B + 1 + threads - 1) / threads;
        compute_offsets_kernel<<<blocks, threads, 0, stream>>>(bv, N, B, offs);
    }

    {
        f32x4* enc4 = (f32x4*)d_out;
        float* tgt  = (float*)d_out + (size_t)total_rows * D;
        float* msk  = (float*)d_out + (size_t)total_rows * (D + 1);
        int threads = 256;                                  // 8 groups/block
        int rows_per_block = (threads >> 5) * ROWS_PER_GROUP; // 32 rows
        dim3 grid((max_len + rows_per_block - 1) / rows_per_block, B, 1);
        gather_pad_kernel<<<grid, threads, 0, stream>>>(
            (const f32x4*)values, y, offs, enc4, tgt, msk, max_len);
    }
}